// Round 6
// baseline (101.515 us; speedup 1.0000x reference)
//
#include <hip/hip_runtime.h>

#define NH 16
#define HD 64
#define LSEQ 2048
#define BQ 256                   // 2 q-tiles merged per block
#define BK 64
#define NBLKQ (LSEQ / BQ)        // 8
#define RS (NH * HD)             // 1024 floats per token row
// k-tiles on a 64-grid offset by -32 from q0: tile j covers keys [256bq - 32 + 64j, +64).
// Group 0 (rows q0..q0+127) needs j=0..2 (min margin 32); group 1 needs j=2..4.
// Dropped keys have weight <= e^-23 relative to the softmax denom.
#define NTILE 5

typedef __bf16 bf16x8 __attribute__((ext_vector_type(8)));
typedef float f32x4 __attribute__((ext_vector_type(4)));

// exp(-8): folds the fixed softmax shift into the mask multiplier; cancels in O/l.
#define EXP_NEG8 0.00033546262790251185f

__global__ __launch_bounds__(1024, 4)
void attn_kernel(const float* __restrict__ Q,
                 const float* __restrict__ K,
                 const float* __restrict__ V,
                 const int* __restrict__ Mk,
                 float* __restrict__ Out)
{
    // K/V double-buffered: [K0|K1|V0|V1], each 64x72 bf16 (9216 B) = 36864 B total.
    // No sP buffer (swapped QK^T keeps P lane-local); no oscr epilogue buffer.
    __shared__ alignas(16) char smem_raw[4 * 64 * 72 * 2];
    __bf16* kvb = (__bf16*)smem_raw;

    const int tid  = threadIdx.x;
    const int wave = tid >> 6;       // 0..15
    const int lane = tid & 63;
    const int ln   = lane & 15;
    const int quad = lane >> 4;
    const int grp  = wave >> 3;      // 0: q-rows [q0,q0+128), active j=0..2; 1: [q0+128,q0+256), j=2..4
    const int w8   = wave & 7;

    const int bq = blockIdx.x & (NBLKQ - 1);
    const int bh = blockIdx.x >> 3;
    const int b  = bh >> 4;
    const int h  = bh & 15;

    const int q0   = bq * BQ;
    const int qrow = q0 + grp * 128 + w8 * 16;

    const size_t bh_off = ((size_t)b * LSEQ) * RS + (size_t)h * HD;
    const float* gQ = Q + bh_off;
    const float* gK = K + bh_off;
    const float* gV = V + bh_off;
    const int*   gM = Mk + (size_t)b * LSEQ;
    float*       gO = Out + bh_off;

    // staging map: tid -> (row 0..63, 16B chunk 0..15); one float4 of K and V per thread
    const int srow = tid >> 4;
    const int sc4  = tid & 15;

    // V key-permutation: PV A-frag slot s (= ch*32 + quad*8 + e) carries actual key
    // pi(s) = (ch*2 + (e>>2))*16 + quad*4 + (e&3). Stage V[k] at column pi^-1(k).
    const int vslot = (srow & 32) | ((srow & 12) << 1) | ((srow & 16) >> 2) | (srow & 3);
    // kappa(d) = ((d>>2)&7)<<3; d = sc4*4+c so d>>2 == sc4 for all 4 c's -> per-thread constant.
    const int vk = vslot ^ ((sc4 & 7) << 3);

    int k0s[NTILE];
#pragma unroll
    for (int j = 0; j < NTILE; ++j) k0s[j] = (q0 - 32 + 64 * j) & (LSEQ - 1);

    // ---- prologue loads: K/V/mask first (feed LDS before first barrier), then Q ----
    // Mask-predicated staging: masked keys contribute p = 0 exactly, so their K/V rows
    // (256 B = 2 HBM lines each) are never fetched; LDS gets zeros instead (must be
    // zeros, not garbage: stale Inf/NaN bf16 * 0 = NaN).
    const int r0 = (k0s[0] + srow) & (LSEQ - 1);
    float4 kreg = {0.f, 0.f, 0.f, 0.f}, vreg = {0.f, 0.f, 0.f, 0.f};
    if (gM[r0] != 0) {
        kreg = *(const float4*)(gK + (size_t)r0 * RS + sc4 * 4);
        vreg = *(const float4*)(gV + (size_t)r0 * RS + sc4 * 4);
    }
    // mask as a wave-wide bitset: one load + ballot per wave per tile
    unsigned long long mbits = __ballot(gM[(k0s[0] + lane) & (LSEQ - 1)] != 0);

    // ---- Q fragments (B-operand), pre-scaled by 1/sqrt(D)
    bf16x8 qfrag[2];
#pragma unroll
    for (int c = 0; c < 2; ++c) {
        const float* src = gQ + (size_t)(qrow + ln) * RS + c * 32 + quad * 8;
        float4 f0 = *(const float4*)(src);
        float4 f1 = *(const float4*)(src + 4);
        bf16x8 t;
        t[0] = (__bf16)(f0.x * 0.125f); t[1] = (__bf16)(f0.y * 0.125f);
        t[2] = (__bf16)(f0.z * 0.125f); t[3] = (__bf16)(f0.w * 0.125f);
        t[4] = (__bf16)(f1.x * 0.125f); t[5] = (__bf16)(f1.y * 0.125f);
        t[6] = (__bf16)(f1.z * 0.125f); t[7] = (__bf16)(f1.w * 0.125f);
        qfrag[c] = t;
    }

    f32x4 o_acc[4];
#pragma unroll
    for (int i = 0; i < 4; ++i) o_acc[i] = f32x4{0.f, 0.f, 0.f, 0.f};
    float l_part = 0.f;   // per-lane: softmax denom for q-row (qrow + ln)

#pragma unroll
    for (int j = 0; j < NTILE; ++j) {
        const int bb = j & 1;
        __bf16* sKb = kvb + bb * 4608;          // [64][72]
        __bf16* sVb = kvb + 9216 + bb * 4608;   // [64][72]: [d][pi^-1(k) ^ kappa(d)]

        // ---- store prefetched tile into this iter's buffer ----
        {
            float4 f = kreg;
            __bf16* dst = sKb + srow * 72 + sc4 * 4;
            dst[0] = (__bf16)f.x; dst[1] = (__bf16)f.y;
            dst[2] = (__bf16)f.z; dst[3] = (__bf16)f.w;
            float4 g = vreg;
            sVb[(sc4 * 4 + 0) * 72 + vk] = (__bf16)g.x;
            sVb[(sc4 * 4 + 1) * 72 + vk] = (__bf16)g.y;
            sVb[(sc4 * 4 + 2) * 72 + vk] = (__bf16)g.z;
            sVb[(sc4 * 4 + 3) * 72 + vk] = (__bf16)g.w;
        }
        const unsigned long long mb = mbits;

        // ---- prefetch next tile (mask-predicated) ----
        if (j + 1 < NTILE) {
            const int k0n = k0s[j + 1];
            const int rn  = (k0n + srow) & (LSEQ - 1);
            kreg = float4{0.f, 0.f, 0.f, 0.f};
            vreg = float4{0.f, 0.f, 0.f, 0.f};
            if (gM[rn] != 0) {
                kreg = *(const float4*)(gK + (size_t)rn * RS + sc4 * 4);
                vreg = *(const float4*)(gV + (size_t)rn * RS + sc4 * 4);
            }
            mbits = __ballot(gM[(k0n + lane) & (LSEQ - 1)] != 0);
        }
        __syncthreads();   // single barrier per tile (double-buffered K/V)

        // group-activity: wave-uniform, compile-time j
        const bool act = grp ? (j >= 2) : (j <= 2);
        if (act) {
            // ---- S^T = K Q^T : lane (ln,quad) gets S[key slot t*16+quad*4+r][q = qrow+ln] ----
            const int k0 = k0s[j];
            f32x4 s[4];
#pragma unroll
            for (int t = 0; t < 4; ++t) {
                f32x4 acc = f32x4{0.f, 0.f, 0.f, 0.f};
#pragma unroll
                for (int ch = 0; ch < 2; ++ch) {
                    bf16x8 ak = *(const bf16x8*)(sKb + (t * 16 + ln) * 72 + ch * 32 + quad * 8);
                    acc = __builtin_amdgcn_mfma_f32_16x16x32_bf16(ak, qfrag[ch], acc, 0, 0, 0);
                }
                s[t] = acc;
            }

            // ---- fixed-shift softmax: p = exp(s - d) * (mask ? e^-8 : 0); lane-local ----
            const int qg = qrow + ln;
#pragma unroll
            for (int t = 0; t < 4; ++t) {
                const unsigned nib = (unsigned)(mb >> (t * 16 + quad * 4)) & 0xFu;
#pragma unroll
                for (int r = 0; r < 4; ++r) {
                    const int kg = (k0 + t * 16 + quad * 4 + r) & (LSEQ - 1);
                    int dd = qg - kg; dd = dd < 0 ? -dd : dd;
                    int d2 = LSEQ - dd; dd = d2 < dd ? d2 : dd;
                    float mmv = ((nib >> r) & 1u) ? EXP_NEG8 : 0.f;
                    float p = __expf(s[t][r] - (float)dd) * mmv;
                    l_part += p;
                    s[t][r] = p;
                }
            }

            // ---- O += P V : P-frag is lane-local (keys pre-permuted into V's columns) ----
#pragma unroll
            for (int ch = 0; ch < 2; ++ch) {
                bf16x8 pa;
#pragma unroll
                for (int e = 0; e < 8; ++e)
                    pa[e] = (__bf16)s[ch * 2 + (e >> 2)][e & 3];
#pragma unroll
                for (int nt = 0; nt < 4; ++nt) {
                    const int vr = nt * 16 + ln;
                    const int vc = (ch * 32 + quad * 8) ^ (((vr >> 2) & 7) << 3);
                    bf16x8 bv = *(const bf16x8*)(sVb + vr * 72 + vc);
                    o_acc[nt] = __builtin_amdgcn_mfma_f32_16x16x32_bf16(pa, bv, o_acc[nt], 0, 0, 0);
                }
            }
        }

        // ---- group 0 epilogue in C_3's shadow: done computing at j=2; normalize + store its
        // 128 rows while group 1 computes tile 3 and tile 4's loads stream. No barrier needed:
        // stores touch only rows [q0, q0+128), disjoint from everything else.
        if (j == 3 && grp == 0) {
            float lf = l_part;
            lf += __shfl_xor(lf, 16, 64);
            lf += __shfl_xor(lf, 32, 64);   // lane (ln,*): full denom for q-row qrow+ln
            float inv[4];
#pragma unroll
            for (int r = 0; r < 4; ++r)
                inv[r] = 1.f / __shfl(lf, quad * 4 + r, 16);   // o_acc rows are qrow + quad*4 + r
#pragma unroll
            for (int nt = 0; nt < 4; ++nt)
#pragma unroll
                for (int r = 0; r < 4; ++r)
                    gO[(size_t)(qrow + quad * 4 + r) * RS + nt * 16 + ln] = o_acc[nt][r] * inv[r];
        }
        // no trailing barrier: next iter writes the other buffer; its barrier orders reuse.
    }

    // ---- group 1 epilogue: only remaining tail (32 KB of stores per block) ----
    if (grp == 1) {
        float lf = l_part;
        lf += __shfl_xor(lf, 16, 64);
        lf += __shfl_xor(lf, 32, 64);
        float inv[4];
#pragma unroll
        for (int r = 0; r < 4; ++r)
            inv[r] = 1.f / __shfl(lf, quad * 4 + r, 16);
#pragma unroll
        for (int nt = 0; nt < 4; ++nt)
#pragma unroll
            for (int r = 0; r < 4; ++r)
                gO[(size_t)(qrow + quad * 4 + r) * RS + nt * 16 + ln] = o_acc[nt][r] * inv[r];
    }
}

extern "C" void kernel_launch(void* const* d_in, const int* in_sizes, int n_in,
                              void* d_out, int out_size, void* d_ws, size_t ws_size,
                              hipStream_t stream) {
    const float* Q  = (const float*)d_in[0];
    const float* K  = (const float*)d_in[1];
    const float* V  = (const float*)d_in[2];
    const int*   Mk = (const int*)d_in[3];
    float*       O  = (float*)d_out;

    dim3 grid(2 * NH * NBLKQ);   // 256 blocks (1 per CU)
    dim3 block(1024);
    attn_kernel<<<grid, block, 0, stream>>>(Q, K, V, Mk, O);
}

// Round 7
// 100.652 us; speedup vs baseline: 1.0086x; 1.0086x over previous
//
#include <hip/hip_runtime.h>

#define NH 16
#define HD 64
#define LSEQ 2048
#define BQ 256                   // 2 q-tiles merged per block
#define BK 64
#define NBLKQ (LSEQ / BQ)        // 8
#define RS (NH * HD)             // 1024 floats per token row
// k-tiles on a 64-grid offset by -32 from q0: tile j covers keys [256bq - 32 + 64j, +64).
// Group 0 (rows q0..q0+127) needs j=0..2 (min margin 32); group 1 needs j=2..4.
// Dropped keys have weight <= e^-23 relative to the softmax denom.
#define NTILE 5

typedef __bf16 bf16x8 __attribute__((ext_vector_type(8)));
typedef float f32x4 __attribute__((ext_vector_type(4)));

// exp(-8): folds the fixed softmax shift into the mask multiplier; cancels in O/l.
#define EXP_NEG8 0.00033546262790251185f

__global__ __launch_bounds__(1024, 4)
void attn_kernel(const float* __restrict__ Q,
                 const float* __restrict__ K,
                 const float* __restrict__ V,
                 const int* __restrict__ Mk,
                 float* __restrict__ Out)
{
    // K/V double-buffered: [K0|K1|V0|V1], each 64x72 bf16 (9216 B) = 36864 B total.
    // No sP buffer (swapped QK^T keeps P lane-local); no oscr epilogue buffer.
    __shared__ alignas(16) char smem_raw[4 * 64 * 72 * 2];
    __bf16* kvb = (__bf16*)smem_raw;

    const int tid  = threadIdx.x;
    const int wave = tid >> 6;       // 0..15
    const int lane = tid & 63;
    const int ln   = lane & 15;
    const int quad = lane >> 4;
    const int grp  = wave >> 3;      // 0: q-rows [q0,q0+128), active j=0..2; 1: [q0+128,q0+256), j=2..4
    const int w8   = wave & 7;

    const int bq = blockIdx.x & (NBLKQ - 1);
    const int bh = blockIdx.x >> 3;
    const int b  = bh >> 4;
    const int h  = bh & 15;

    const int q0   = bq * BQ;
    const int qrow = q0 + grp * 128 + w8 * 16;

    const size_t bh_off = ((size_t)b * LSEQ) * RS + (size_t)h * HD;
    const float* gQ = Q + bh_off;
    const float* gK = K + bh_off;
    const float* gV = V + bh_off;
    const int*   gM = Mk + (size_t)b * LSEQ;
    float*       gO = Out + bh_off;

    // staging map: tid -> (row 0..63, 16B chunk 0..15); one float4 of K and V per thread
    const int srow = tid >> 4;
    const int sc4  = tid & 15;

    // V key-permutation: PV A-frag slot s (= ch*32 + quad*8 + e) carries actual key
    // pi(s) = (ch*2 + (e>>2))*16 + quad*4 + (e&3). Stage V[k] at column pi^-1(k).
    const int vslot = (srow & 32) | ((srow & 12) << 1) | ((srow & 16) >> 2) | (srow & 3);
    // kappa(d) = ((d>>2)&7)<<3; d = sc4*4+c so d>>2 == sc4 for all 4 c's -> per-thread constant.
    const int vk = vslot ^ ((sc4 & 7) << 3);

    int k0s[NTILE];
#pragma unroll
    for (int j = 0; j < NTILE; ++j) k0s[j] = (q0 - 32 + 64 * j) & (LSEQ - 1);

    // ---- ALL tile masks up front: 5 independent broadcast loads -> ballots, one round-trip.
    // bit r of mba[j] == mask state of row r of tile j. Keeps the mask OFF the prefetch
    // critical path (R6's regression: per-tile mask load serialized before K/V loads).
    unsigned long long mba[NTILE];
#pragma unroll
    for (int j = 0; j < NTILE; ++j)
        mba[j] = __ballot(gM[(k0s[j] + lane) & (LSEQ - 1)] != 0);

    // ---- prologue K/V for tile 0, mask-predicated by register bit: masked rows (p = 0
    // exactly) are never fetched; LDS gets zeros (must be zeros: stale Inf * 0 = NaN).
    const int r0 = (k0s[0] + srow) & (LSEQ - 1);
    float4 kreg = {0.f, 0.f, 0.f, 0.f}, vreg = {0.f, 0.f, 0.f, 0.f};
    if ((mba[0] >> srow) & 1) {
        kreg = *(const float4*)(gK + (size_t)r0 * RS + sc4 * 4);
        vreg = *(const float4*)(gV + (size_t)r0 * RS + sc4 * 4);
    }

    // ---- Q fragments (B-operand), pre-scaled by 1/sqrt(D)
    bf16x8 qfrag[2];
#pragma unroll
    for (int c = 0; c < 2; ++c) {
        const float* src = gQ + (size_t)(qrow + ln) * RS + c * 32 + quad * 8;
        float4 f0 = *(const float4*)(src);
        float4 f1 = *(const float4*)(src + 4);
        bf16x8 t;
        t[0] = (__bf16)(f0.x * 0.125f); t[1] = (__bf16)(f0.y * 0.125f);
        t[2] = (__bf16)(f0.z * 0.125f); t[3] = (__bf16)(f0.w * 0.125f);
        t[4] = (__bf16)(f1.x * 0.125f); t[5] = (__bf16)(f1.y * 0.125f);
        t[6] = (__bf16)(f1.z * 0.125f); t[7] = (__bf16)(f1.w * 0.125f);
        qfrag[c] = t;
    }

    f32x4 o_acc[4];
#pragma unroll
    for (int i = 0; i < 4; ++i) o_acc[i] = f32x4{0.f, 0.f, 0.f, 0.f};
    float l_part = 0.f;   // per-lane: softmax denom for q-row (qrow + ln)

#pragma unroll
    for (int j = 0; j < NTILE; ++j) {
        const int bb = j & 1;
        __bf16* sKb = kvb + bb * 4608;          // [64][72]
        __bf16* sVb = kvb + 9216 + bb * 4608;   // [64][72]: [d][pi^-1(k) ^ kappa(d)]

        // ---- store prefetched tile into this iter's buffer ----
        {
            float4 f = kreg;
            __bf16* dst = sKb + srow * 72 + sc4 * 4;
            dst[0] = (__bf16)f.x; dst[1] = (__bf16)f.y;
            dst[2] = (__bf16)f.z; dst[3] = (__bf16)f.w;
            float4 g = vreg;
            sVb[(sc4 * 4 + 0) * 72 + vk] = (__bf16)g.x;
            sVb[(sc4 * 4 + 1) * 72 + vk] = (__bf16)g.y;
            sVb[(sc4 * 4 + 2) * 72 + vk] = (__bf16)g.z;
            sVb[(sc4 * 4 + 3) * 72 + vk] = (__bf16)g.w;
        }
        const unsigned long long mb = mba[j];

        // ---- prefetch next tile: predicate is a REGISTER bit, loads issue immediately ----
        if (j + 1 < NTILE) {
            const int k0n = k0s[j + 1];
            const int rn  = (k0n + srow) & (LSEQ - 1);
            kreg = float4{0.f, 0.f, 0.f, 0.f};
            vreg = float4{0.f, 0.f, 0.f, 0.f};
            if ((mba[j + 1] >> srow) & 1) {
                kreg = *(const float4*)(gK + (size_t)rn * RS + sc4 * 4);
                vreg = *(const float4*)(gV + (size_t)rn * RS + sc4 * 4);
            }
        }
        __syncthreads();   // single barrier per tile (double-buffered K/V)

        // group-activity: wave-uniform, compile-time j
        const bool act = grp ? (j >= 2) : (j <= 2);
        if (act) {
            // ---- S^T = K Q^T : lane (ln,quad) gets S[key slot t*16+quad*4+r][q = qrow+ln] ----
            const int k0 = k0s[j];
            f32x4 s[4];
#pragma unroll
            for (int t = 0; t < 4; ++t) {
                f32x4 acc = f32x4{0.f, 0.f, 0.f, 0.f};
#pragma unroll
                for (int ch = 0; ch < 2; ++ch) {
                    bf16x8 ak = *(const bf16x8*)(sKb + (t * 16 + ln) * 72 + ch * 32 + quad * 8);
                    acc = __builtin_amdgcn_mfma_f32_16x16x32_bf16(ak, qfrag[ch], acc, 0, 0, 0);
                }
                s[t] = acc;
            }

            // ---- fixed-shift softmax: p = exp(s - d) * (mask ? e^-8 : 0); lane-local ----
            const int qg = qrow + ln;
#pragma unroll
            for (int t = 0; t < 4; ++t) {
                const unsigned nib = (unsigned)(mb >> (t * 16 + quad * 4)) & 0xFu;
#pragma unroll
                for (int r = 0; r < 4; ++r) {
                    const int kg = (k0 + t * 16 + quad * 4 + r) & (LSEQ - 1);
                    int dd = qg - kg; dd = dd < 0 ? -dd : dd;
                    int d2 = LSEQ - dd; dd = d2 < dd ? d2 : dd;
                    float mmv = ((nib >> r) & 1u) ? EXP_NEG8 : 0.f;
                    float p = __expf(s[t][r] - (float)dd) * mmv;
                    l_part += p;
                    s[t][r] = p;
                }
            }

            // ---- O += P V : P-frag is lane-local (keys pre-permuted into V's columns) ----
#pragma unroll
            for (int ch = 0; ch < 2; ++ch) {
                bf16x8 pa;
#pragma unroll
                for (int e = 0; e < 8; ++e)
                    pa[e] = (__bf16)s[ch * 2 + (e >> 2)][e & 3];
#pragma unroll
                for (int nt = 0; nt < 4; ++nt) {
                    const int vr = nt * 16 + ln;
                    const int vc = (ch * 32 + quad * 8) ^ (((vr >> 2) & 7) << 3);
                    bf16x8 bv = *(const bf16x8*)(sVb + vr * 72 + vc);
                    o_acc[nt] = __builtin_amdgcn_mfma_f32_16x16x32_bf16(pa, bv, o_acc[nt], 0, 0, 0);
                }
            }
        }

        // ---- group 0 epilogue in C_3's shadow: done computing at j=2; normalize + store its
        // 128 rows while group 1 computes tile 3 and tile 4's loads stream. No barrier needed:
        // stores touch only rows [q0, q0+128), disjoint from everything else.
        if (j == 3 && grp == 0) {
            float lf = l_part;
            lf += __shfl_xor(lf, 16, 64);
            lf += __shfl_xor(lf, 32, 64);   // lane (ln,*): full denom for q-row qrow+ln
            float inv[4];
#pragma unroll
            for (int r = 0; r < 4; ++r)
                inv[r] = 1.f / __shfl(lf, quad * 4 + r, 16);   // o_acc rows are qrow + quad*4 + r
#pragma unroll
            for (int nt = 0; nt < 4; ++nt)
#pragma unroll
                for (int r = 0; r < 4; ++r)
                    gO[(size_t)(qrow + quad * 4 + r) * RS + nt * 16 + ln] = o_acc[nt][r] * inv[r];
        }
        // no trailing barrier: next iter writes the other buffer; its barrier orders reuse.
    }

    // ---- group 1 epilogue: only remaining tail (32 KB of stores per block) ----
    if (grp == 1) {
        float lf = l_part;
        lf += __shfl_xor(lf, 16, 64);
        lf += __shfl_xor(lf, 32, 64);
        float inv[4];
#pragma unroll
        for (int r = 0; r < 4; ++r)
            inv[r] = 1.f / __shfl(lf, quad * 4 + r, 16);
#pragma unroll
        for (int nt = 0; nt < 4; ++nt)
#pragma unroll
            for (int r = 0; r < 4; ++r)
                gO[(size_t)(qrow + quad * 4 + r) * RS + nt * 16 + ln] = o_acc[nt][r] * inv[r];
    }
}

extern "C" void kernel_launch(void* const* d_in, const int* in_sizes, int n_in,
                              void* d_out, int out_size, void* d_ws, size_t ws_size,
                              hipStream_t stream) {
    const float* Q  = (const float*)d_in[0];
    const float* K  = (const float*)d_in[1];
    const float* V  = (const float*)d_in[2];
    const int*   Mk = (const int*)d_in[3];
    float*       O  = (float*)d_out;

    dim3 grid(2 * NH * NBLKQ);   // 256 blocks (1 per CU)
    dim3 block(1024);
    attn_kernel<<<grid, block, 0, stream>>>(Q, K, V, Mk, O);
}

// Round 8
// 97.530 us; speedup vs baseline: 1.0409x; 1.0320x over previous
//
#include <hip/hip_runtime.h>

#define NH 16
#define HD 64
#define LSEQ 2048
#define BQ 256                   // 2 q-tiles merged per block
#define BK 64
#define NBLKQ (LSEQ / BQ)        // 8
#define RS (NH * HD)             // 1024 floats per token row
// k-tiles on a 64-grid offset by -32 from q0: tile j covers keys [256bq - 32 + 64j, +64).
// Group 0 (rows q0..q0+127) needs j=0..2 (min margin 32); group 1 needs j=2..4.
// Dropped keys have weight <= e^-23 relative to the softmax denom.
#define NTILE 5

typedef __bf16 bf16x8 __attribute__((ext_vector_type(8)));
typedef float f32x4 __attribute__((ext_vector_type(4)));

// exp(-8): folds the fixed softmax shift into the mask multiplier; cancels in O/l.
#define EXP_NEG8 0.00033546262790251185f

// NOTE (R6/R7 lesson): mask-predicated K/V staging (skip loads for masked rows) cuts
// ~21 MB of HBM traffic but REGRESSES +2.6..3.5 us, even with the mask hoisted to
// prologue ballots and a pure register predicate. The divergent branch around the
// staging loads breaks prefetch issue clustering and the gappy row gather loses DRAM
// page efficiency. Keep staging unconditional.

__global__ __launch_bounds__(1024, 4)
void attn_kernel(const float* __restrict__ Q,
                 const float* __restrict__ K,
                 const float* __restrict__ V,
                 const int* __restrict__ Mk,
                 float* __restrict__ Out)
{
    // K/V double-buffered: [K0|K1|V0|V1], each 64x72 bf16 (9216 B) = 36864 B total.
    // No sP buffer (swapped QK^T keeps P lane-local); no oscr epilogue buffer
    // (direct per-lane dword stores: each quad writes a 64B run, L2 write-combines).
    __shared__ alignas(16) char smem_raw[4 * 64 * 72 * 2];
    __bf16* kvb = (__bf16*)smem_raw;

    const int tid  = threadIdx.x;
    const int wave = tid >> 6;       // 0..15
    const int lane = tid & 63;
    const int ln   = lane & 15;
    const int quad = lane >> 4;
    const int grp  = wave >> 3;      // 0: q-rows [q0,q0+128), active j=0..2; 1: [q0+128,q0+256), j=2..4
    const int w8   = wave & 7;

    const int bq = blockIdx.x & (NBLKQ - 1);
    const int bh = blockIdx.x >> 3;
    const int b  = bh >> 4;
    const int h  = bh & 15;

    const int q0   = bq * BQ;
    const int qrow = q0 + grp * 128 + w8 * 16;

    const size_t bh_off = ((size_t)b * LSEQ) * RS + (size_t)h * HD;
    const float* gQ = Q + bh_off;
    const float* gK = K + bh_off;
    const float* gV = V + bh_off;
    const int*   gM = Mk + (size_t)b * LSEQ;
    float*       gO = Out + bh_off;

    // staging map: tid -> (row 0..63, 16B chunk 0..15); one float4 of K and V per thread
    const int srow = tid >> 4;
    const int sc4  = tid & 15;

    // V key-permutation: PV A-frag slot s (= ch*32 + quad*8 + e) carries actual key
    // pi(s) = (ch*2 + (e>>2))*16 + quad*4 + (e&3). Stage V[k] at column pi^-1(k).
    const int vslot = (srow & 32) | ((srow & 12) << 1) | ((srow & 16) >> 2) | (srow & 3);
    // kappa(d) = ((d>>2)&7)<<3; d = sc4*4+c so d>>2 == sc4 for all 4 c's -> per-thread constant.
    const int vk = vslot ^ ((sc4 & 7) << 3);

    int k0s[NTILE];
#pragma unroll
    for (int j = 0; j < NTILE; ++j) k0s[j] = (q0 - 32 + 64 * j) & (LSEQ - 1);

    // ---- prologue loads: K/V/mask first (feed LDS before first barrier), then Q ----
    const int r0 = (k0s[0] + srow) & (LSEQ - 1);
    float4 kreg = *(const float4*)(gK + (size_t)r0 * RS + sc4 * 4);
    float4 vreg = *(const float4*)(gV + (size_t)r0 * RS + sc4 * 4);
    // mask as a wave-wide bitset: one load + ballot per wave per tile
    unsigned long long mbits = __ballot(gM[(k0s[0] + lane) & (LSEQ - 1)] != 0);

    // ---- Q fragments (B-operand), pre-scaled by 1/sqrt(D)
    bf16x8 qfrag[2];
#pragma unroll
    for (int c = 0; c < 2; ++c) {
        const float* src = gQ + (size_t)(qrow + ln) * RS + c * 32 + quad * 8;
        float4 f0 = *(const float4*)(src);
        float4 f1 = *(const float4*)(src + 4);
        bf16x8 t;
        t[0] = (__bf16)(f0.x * 0.125f); t[1] = (__bf16)(f0.y * 0.125f);
        t[2] = (__bf16)(f0.z * 0.125f); t[3] = (__bf16)(f0.w * 0.125f);
        t[4] = (__bf16)(f1.x * 0.125f); t[5] = (__bf16)(f1.y * 0.125f);
        t[6] = (__bf16)(f1.z * 0.125f); t[7] = (__bf16)(f1.w * 0.125f);
        qfrag[c] = t;
    }

    f32x4 o_acc[4];
#pragma unroll
    for (int i = 0; i < 4; ++i) o_acc[i] = f32x4{0.f, 0.f, 0.f, 0.f};
    float l_part = 0.f;   // per-lane: softmax denom for q-row (qrow + ln)

#pragma unroll
    for (int j = 0; j < NTILE; ++j) {
        const int bb = j & 1;
        __bf16* sKb = kvb + bb * 4608;          // [64][72]
        __bf16* sVb = kvb + 9216 + bb * 4608;   // [64][72]: [d][pi^-1(k) ^ kappa(d)]

        // ---- store prefetched tile into this iter's buffer ----
        {
            float4 f = kreg;
            __bf16* dst = sKb + srow * 72 + sc4 * 4;
            dst[0] = (__bf16)f.x; dst[1] = (__bf16)f.y;
            dst[2] = (__bf16)f.z; dst[3] = (__bf16)f.w;
            float4 g = vreg;
            sVb[(sc4 * 4 + 0) * 72 + vk] = (__bf16)g.x;
            sVb[(sc4 * 4 + 1) * 72 + vk] = (__bf16)g.y;
            sVb[(sc4 * 4 + 2) * 72 + vk] = (__bf16)g.z;
            sVb[(sc4 * 4 + 3) * 72 + vk] = (__bf16)g.w;
        }
        const unsigned long long mb = mbits;

        // ---- prefetch next tile (unconditional: see R6/R7 note above) ----
        if (j + 1 < NTILE) {
            const int k0n = k0s[j + 1];
            const int rn  = (k0n + srow) & (LSEQ - 1);
            kreg = *(const float4*)(gK + (size_t)rn * RS + sc4 * 4);
            vreg = *(const float4*)(gV + (size_t)rn * RS + sc4 * 4);
            mbits = __ballot(gM[(k0n + lane) & (LSEQ - 1)] != 0);
        }
        __syncthreads();   // single barrier per tile (double-buffered K/V)

        // group-activity: wave-uniform, compile-time j
        const bool act = grp ? (j >= 2) : (j <= 2);
        if (act) {
            // ---- S^T = K Q^T : lane (ln,quad) gets S[key slot t*16+quad*4+r][q = qrow+ln] ----
            const int k0 = k0s[j];
            f32x4 s[4];
#pragma unroll
            for (int t = 0; t < 4; ++t) {
                f32x4 acc = f32x4{0.f, 0.f, 0.f, 0.f};
#pragma unroll
                for (int ch = 0; ch < 2; ++ch) {
                    bf16x8 ak = *(const bf16x8*)(sKb + (t * 16 + ln) * 72 + ch * 32 + quad * 8);
                    acc = __builtin_amdgcn_mfma_f32_16x16x32_bf16(ak, qfrag[ch], acc, 0, 0, 0);
                }
                s[t] = acc;
            }

            // ---- fixed-shift softmax: p = exp(s - d) * (mask ? e^-8 : 0); lane-local ----
            const int qg = qrow + ln;
#pragma unroll
            for (int t = 0; t < 4; ++t) {
                const unsigned nib = (unsigned)(mb >> (t * 16 + quad * 4)) & 0xFu;
#pragma unroll
                for (int r = 0; r < 4; ++r) {
                    const int kg = (k0 + t * 16 + quad * 4 + r) & (LSEQ - 1);
                    int dd = qg - kg; dd = dd < 0 ? -dd : dd;
                    int d2 = LSEQ - dd; dd = d2 < dd ? d2 : dd;
                    float mmv = ((nib >> r) & 1u) ? EXP_NEG8 : 0.f;
                    float p = __expf(s[t][r] - (float)dd) * mmv;
                    l_part += p;
                    s[t][r] = p;
                }
            }

            // ---- O += P V : P-frag is lane-local (keys pre-permuted into V's columns) ----
#pragma unroll
            for (int ch = 0; ch < 2; ++ch) {
                bf16x8 pa;
#pragma unroll
                for (int e = 0; e < 8; ++e)
                    pa[e] = (__bf16)s[ch * 2 + (e >> 2)][e & 3];
#pragma unroll
                for (int nt = 0; nt < 4; ++nt) {
                    const int vr = nt * 16 + ln;
                    const int vc = (ch * 32 + quad * 8) ^ (((vr >> 2) & 7) << 3);
                    bf16x8 bv = *(const bf16x8*)(sVb + vr * 72 + vc);
                    o_acc[nt] = __builtin_amdgcn_mfma_f32_16x16x32_bf16(pa, bv, o_acc[nt], 0, 0, 0);
                }
            }
        }

        // ---- group 0 epilogue in C_3's shadow: done computing at j=2; normalize + store its
        // 128 rows while group 1 computes tile 3 and tile 4's loads stream. No barrier needed:
        // stores touch only rows [q0, q0+128), disjoint from everything else.
        if (j == 3 && grp == 0) {
            float lf = l_part;
            lf += __shfl_xor(lf, 16, 64);
            lf += __shfl_xor(lf, 32, 64);   // lane (ln,*): full denom for q-row qrow+ln
            float inv[4];
#pragma unroll
            for (int r = 0; r < 4; ++r)
                inv[r] = 1.f / __shfl(lf, quad * 4 + r, 16);   // o_acc rows are qrow + quad*4 + r
#pragma unroll
            for (int nt = 0; nt < 4; ++nt)
#pragma unroll
                for (int r = 0; r < 4; ++r)
                    gO[(size_t)(qrow + quad * 4 + r) * RS + nt * 16 + ln] = o_acc[nt][r] * inv[r];
        }
        // no trailing barrier: next iter writes the other buffer; its barrier orders reuse.
    }

    // ---- group 1 epilogue: only remaining tail (32 KB of stores per block) ----
    if (grp == 1) {
        float lf = l_part;
        lf += __shfl_xor(lf, 16, 64);
        lf += __shfl_xor(lf, 32, 64);
        float inv[4];
#pragma unroll
        for (int r = 0; r < 4; ++r)
            inv[r] = 1.f / __shfl(lf, quad * 4 + r, 16);
#pragma unroll
        for (int nt = 0; nt < 4; ++nt)
#pragma unroll
            for (int r = 0; r < 4; ++r)
                gO[(size_t)(qrow + quad * 4 + r) * RS + nt * 16 + ln] = o_acc[nt][r] * inv[r];
    }
}

extern "C" void kernel_launch(void* const* d_in, const int* in_sizes, int n_in,
                              void* d_out, int out_size, void* d_ws, size_t ws_size,
                              hipStream_t stream) {
    const float* Q  = (const float*)d_in[0];
    const float* K  = (const float*)d_in[1];
    const float* V  = (const float*)d_in[2];
    const int*   Mk = (const int*)d_in[3];
    float*       O  = (float*)d_out;

    dim3 grid(2 * NH * NBLKQ);   // 256 blocks (1 per CU)
    dim3 block(1024);
    attn_kernel<<<grid, block, 0, stream>>>(Q, K, V, Mk, O);
}